// Round 3
// baseline (244.540 us; speedup 1.0000x reference)
//
#include <hip/hip_runtime.h>
#include <hip/hip_bf16.h>
#include <cstdint>

// Problem: B=4, T=1024, C=1024, H=16, D=64, MAX_LEN=1024, NPOS=2047
// Pipeline (R13, resubmitted unchanged in R14 -- GPU timeout, never measured):
//   cvt3: x, qkv_w, proj_w fp32 -> bf16 in ws (one pass)
//   table_reduce rel_pos_emb -> (2047,16)
//   gemm_bt<0>: qkv = xb @ qwb^T + b -> scatter bf16; Q,K (B,H,T,D), V (B,H,D,T)
//   attn_mfma: flash causal, 128-query blocks (8 waves), S^T-softmax -> y bf16
//   gemm_bt<1>: out = y @ pwb^T + b -> fp32 d_out
//
// R12 measured: 169.8us total. gemm_bt<0> 38.5us MfmaUtil 31.9% occ 74.8%
// (gload_lds theory CONFIRMED). attn_mfma now 50% of runtime: 84.9us,
// MfmaUtil 21.4%, FETCH 24.8MB (4.6% HBM) -> barrier-lockstep bound.
//
// R13 change: attn drops K/V LDS staging (K+V per head = 512KB, L2-fits;
// Common-mistake #7 / m169: staging L2-fit data is pure overhead). K,V MFMA
// fragments read DIRECTLY from global (identical per-lane pattern as the old
// ds_reads). Both per-tile barriers deleted -> 8 waves fully independent
// (Ps is wave-private; single barrier remains after cooperative tb load,
// which was previously covered by the loop's first barrier).
//
// Workspace layout (bytes):
//   xb   @ 0         : 4096x1024 bf16  (8 MB)
//   qwb  @ 8388608   : 3072x1024 bf16  (6 MB)
//   pwb  @ 14680064  : 1024x1024 bf16  (2 MB)
//   table@ 16777216  : 2047x16 f32     (128 KB)
//   qkvb @ 16908288  : (3,4,16,64K) bf16 (24 MB)
//   y    @ 42074112  : 4096x1024 bf16  (8 MB)

typedef __bf16 bf16x8 __attribute__((ext_vector_type(8)));
typedef float f32x4 __attribute__((ext_vector_type(4)));

__device__ __forceinline__ float bf2f(unsigned short u) {
    return __uint_as_float(((unsigned)u) << 16);
}
__device__ __forceinline__ unsigned short f2bf(float f) {
    __hip_bfloat16 h = __float2bfloat16(f);
    return *reinterpret_cast<unsigned short*>(&h);
}
__device__ __forceinline__ int4 cvt8(float4 a, float4 b) {
    union { unsigned short s[8]; int4 v; } u;
    u.s[0] = f2bf(a.x); u.s[1] = f2bf(a.y); u.s[2] = f2bf(a.z); u.s[3] = f2bf(a.w);
    u.s[4] = f2bf(b.x); u.s[5] = f2bf(b.y); u.s[6] = f2bf(b.z); u.s[7] = f2bf(b.w);
    return u.v;
}

// async global->LDS, 16B per lane. LDS dest must be linear base+lane*16.
__device__ __forceinline__ void gload16(const void* g, void* l) {
    __builtin_amdgcn_global_load_lds(
        reinterpret_cast<const __attribute__((address_space(1))) unsigned int*>(
            reinterpret_cast<uintptr_t>(g)),
        reinterpret_cast<__attribute__((address_space(3))) unsigned int*>(
            reinterpret_cast<uintptr_t>(l)),
        16, 0, 0);
}

// ---------------- fp32 -> bf16 one-shot convert (x, qkv_w, proj_w) ----------
__global__ __launch_bounds__(256) void cvt3(const float* __restrict__ x,
                                            const float* __restrict__ w1,
                                            const float* __restrict__ w2,
                                            unsigned short* __restrict__ ox,
                                            unsigned short* __restrict__ ow1,
                                            unsigned short* __restrict__ ow2) {
    const int i = blockIdx.x * 256 + threadIdx.x;
    const float* s; unsigned short* d; int li;
    if (i < 524288)      { s = x;  d = ox;  li = i; }
    else if (i < 917504) { s = w1; d = ow1; li = i - 524288; }
    else                 { s = w2; d = ow2; li = i - 917504; }
    const float4 a = *(const float4*)(s + (size_t)li * 8);
    const float4 b = *(const float4*)(s + (size_t)li * 8 + 4);
    *(int4*)(d + (size_t)li * 8) = cvt8(a, b);
}

// ---------------- rel_pos_emb (2047,1024) -> table (2047,16) ----------------
__global__ __launch_bounds__(256) void table_reduce(const float* __restrict__ rel,
                                                    float* __restrict__ table) {
    const int p = blockIdx.x;
    const int tid = threadIdx.x, lane = tid & 63, wave = tid >> 6;
    const float* r = rel + (size_t)p * 1024;
    float s[4];
#pragma unroll
    for (int k = 0; k < 4; ++k) s[k] = r[tid + 256 * k];
#pragma unroll
    for (int k = 0; k < 4; ++k) {
        float v = s[k];
        for (int o = 32; o; o >>= 1) v += __shfl_xor(v, o, 64);
        if (lane == 0) table[p * 16 + wave + 4 * k] = v;
    }
}

// ---------------- bf16 MFMA GEMM: C = A B^T + bias (gload_lds / m97) --------
// Unchanged from R12 (measured win: MfmaUtil 31.9%, occ 74.8%).
template <int EPI>
__global__ __launch_bounds__(512) void gemm_bt(const unsigned short* __restrict__ A,
                                               const unsigned short* __restrict__ B,
                                               const float* __restrict__ bias,
                                               unsigned short* __restrict__ outb,
                                               float* __restrict__ outf,
                                               int M, int N, int K) {
    __shared__ __attribute__((aligned(16))) unsigned short As[128 * 32];
    __shared__ __attribute__((aligned(16))) unsigned short Bs[128 * 32];
    const int bm = blockIdx.x * 128, bn = blockIdx.y * 128;
    const int tid = threadIdx.x, lane = tid & 63, wave = tid >> 6;
    const int wr = wave & 1, wc = wave >> 1;  // wc in 0..3
    const int quad = lane >> 4, lm = lane & 15;

    const int srow = tid >> 2;        // 0..127
    const int scol = (tid & 3) * 8;   // shorts
    const unsigned short* Ap = A + (size_t)(bm + srow) * K + scol;
    const unsigned short* Bp = B + (size_t)(bn + srow) * K + scol;
    unsigned short* AsW = &As[tid * 8];   // == row srow, col scol (linear)
    unsigned short* BsW = &Bs[tid * 8];

    f32x4 acc[4][2];
#pragma unroll
    for (int r = 0; r < 4; ++r)
#pragma unroll
        for (int c = 0; c < 2; ++c) acc[r][c] = (f32x4){0.f, 0.f, 0.f, 0.f};

    for (int kk = 0; kk < K; kk += 32) {
        gload16(Ap + kk, AsW);
        gload16(Bp + kk, BsW);
        __syncthreads();  // compiler emits vmcnt(0) drain before s_barrier

        bf16x8 af[4], bfr[2];
#pragma unroll
        for (int r = 0; r < 4; ++r)
            af[r] = *(const bf16x8*)(&As[(64 * wr + 16 * r + lm) * 32 + quad * 8]);
#pragma unroll
        for (int c = 0; c < 2; ++c)
            bfr[c] = *(const bf16x8*)(&Bs[(32 * wc + 16 * c + lm) * 32 + quad * 8]);
#pragma unroll
        for (int r = 0; r < 4; ++r)
#pragma unroll
            for (int c = 0; c < 2; ++c)
                acc[r][c] = __builtin_amdgcn_mfma_f32_16x16x32_bf16(af[r], bfr[c], acc[r][c], 0, 0, 0);
        __syncthreads();
    }

    // C/D layout: col = lane&15, row = (lane>>4)*4 + reg
#pragma unroll
    for (int r = 0; r < 4; ++r)
#pragma unroll
        for (int c = 0; c < 2; ++c)
#pragma unroll
            for (int i = 0; i < 4; ++i) {
                const int row = bm + 64 * wr + 16 * r + quad * 4 + i;
                const int col = bn + 32 * wc + 16 * c + lm;
                const float v = acc[r][c][i] + bias[col];
                if (EPI == 0) {
                    const int b = row >> 10, t = row & 1023;
                    const int s3 = col >> 10, rem = col & 1023;
                    const int h = rem >> 6, d = rem & 63;
                    const size_t base = (((size_t)s3 * 4 + b) * 16 + h) * 65536;
                    const size_t off = base + (s3 == 2 ? (size_t)d * 1024 + t
                                                       : (size_t)t * 64 + d);
                    outb[off] = f2bf(v);
                } else {
                    outf[(size_t)row * N + col] = v;
                }
            }
}

// ---------------- MFMA flash causal attention, S^T-softmax ----------------
// grid (B*H, T/128), block 512 = 8 waves. Wave w owns queries qb+16w..+15.
// R13: NO K/V LDS staging (L2-fit data, m169). K,V fragments read directly
// from global with the same per-lane pattern the ds_reads used. No per-tile
// barriers -- waves fully independent. Single barrier after tb load.
// S^T = K Q^T: s[nb][i] = S^T[j = kt*64+nb*16+quad*4+i][q = qb+w*16+lm].
// Per lane: ONE query (q const), scalar mi/li, 2-shfl reductions. P goes
// through wave-private Ps (layout change C->A-frag), PV reads A=P b128,
// B=V^T b128 from global.
__global__ __launch_bounds__(512) void attn_mfma(const unsigned short* __restrict__ qkvb,
                                                 const float* __restrict__ table,
                                                 unsigned short* __restrict__ y) {
    const int bh = blockIdx.x, b = bh >> 4, h = bh & 15;
    const int qb = (7 - blockIdx.y) * 128;  // longest blocks first
    const int tid = threadIdx.x, lane = tid & 63, wave = tid >> 6;
    const int quad = lane >> 4, lm = lane & 15;

    __shared__ __attribute__((aligned(16))) unsigned short Ps[8][16][72];   // [wave][q][j]
    __shared__ float tb[1280];

    const unsigned short* Qg  = qkvb + ((size_t)(b)*16 + h) * 65536;       // [t][d]
    const unsigned short* Kg  = qkvb + ((size_t)(4 + b)*16 + h) * 65536;   // [t][d]
    const unsigned short* Vtg = qkvb + ((size_t)(8 + b)*16 + h) * 65536;   // [d][t]

    // Q fragment (serves as MFMA B-operand; same register layout)
    const bf16x8 qf0 = *(const bf16x8*)(Qg + (size_t)(qb + wave * 16 + lm) * 64 + quad * 8);
    const bf16x8 qf1 = *(const bf16x8*)(Qg + (size_t)(qb + wave * 16 + lm) * 64 + 32 + quad * 8);

    const int tbn = qb + 255;
    for (int i = tid; i < tbn; i += 512) tb[i] = table[(896 + i) * 16 + h];
    __syncthreads();  // tb ready; no further block-wide sync needed

    f32x4 oacc[4];
#pragma unroll
    for (int nb = 0; nb < 4; ++nb) oacc[nb] = (f32x4){0.f, 0.f, 0.f, 0.f};
    float mi = -1e30f, li = 0.f;  // per-lane: one query q = qb + wave*16 + lm

    const int q = qb + wave * 16 + lm;
    const int ktiles = qb / 64 + 2;
    for (int kt = 0; kt < ktiles; ++kt) {
        // S^T = K Q^T : A = K rows (j) straight from global (L2-resident)
        f32x4 s[4];
#pragma unroll
        for (int nb = 0; nb < 4; ++nb) {
            const size_t krow = (size_t)(kt * 64 + nb * 16 + lm) * 64;
            bf16x8 k0 = *(const bf16x8*)(Kg + krow + quad * 8);
            bf16x8 k1 = *(const bf16x8*)(Kg + krow + 32 + quad * 8);
            s[nb] = (f32x4){0.f, 0.f, 0.f, 0.f};
            s[nb] = __builtin_amdgcn_mfma_f32_16x16x32_bf16(k0, qf0, s[nb], 0, 0, 0);
            s[nb] = __builtin_amdgcn_mfma_f32_16x16x32_bf16(k1, qf1, s[nb], 0, 0, 0);
        }

        // scale + rel-pos bias + causal mask (q lane-constant)
        const int jb0 = kt * 64 + quad * 4;
#pragma unroll
        for (int nb = 0; nb < 4; ++nb)
#pragma unroll
            for (int i = 0; i < 4; ++i) {
                const int j = jb0 + nb * 16 + i;
                const float v = fmaf(s[nb][i], 0.125f, tb[q - j + 127]);
                s[nb][i] = (j <= q) ? v : -1e30f;
            }

        // online softmax: local 16-reg tree + cross-quad shuffles (xor 16,32)
        float mx = -1e30f;
#pragma unroll
        for (int nb = 0; nb < 4; ++nb)
#pragma unroll
            for (int i = 0; i < 4; ++i) mx = fmaxf(mx, s[nb][i]);
        mx = fmaxf(mx, __shfl_xor(mx, 16, 64));
        mx = fmaxf(mx, __shfl_xor(mx, 32, 64));
        const float mnew = fmaxf(mi, mx);
        const float alpha = __expf(mi - mnew);
        mi = mnew;
#pragma unroll
        for (int nb = 0; nb < 4; ++nb)
#pragma unroll
            for (int i = 0; i < 4; ++i) s[nb][i] = __expf(s[nb][i] - mnew);
        float ps = 0.f;
#pragma unroll
        for (int nb = 0; nb < 4; ++nb)
            ps += (s[nb][0] + s[nb][1]) + (s[nb][2] + s[nb][3]);
        ps += __shfl_xor(ps, 16, 64);
        ps += __shfl_xor(ps, 32, 64);
        li = li * alpha + ps;

        // P store: [wave][q=lm][j], 4 consecutive j per (nb,quad) -> b64
        // (wave-private LDS round-trip; compiler orders via lgkmcnt, no barrier)
#pragma unroll
        for (int nb = 0; nb < 4; ++nb) {
            union { unsigned short u[4]; int2 v; } p4;
            p4.u[0] = f2bf(s[nb][0]);
            p4.u[1] = f2bf(s[nb][1]);
            p4.u[2] = f2bf(s[nb][2]);
            p4.u[3] = f2bf(s[nb][3]);
            *(int2*)(&Ps[wave][lm][nb * 16 + quad * 4]) = p4.v;
        }

        // broadcast alpha (at lane q=lm) to C-layout rows (q=quad*4+i)
        float alr[4];
#pragma unroll
        for (int i = 0; i < 4; ++i) alr[i] = __shfl(alpha, quad * 4 + i, 64);
#pragma unroll
        for (int nb = 0; nb < 4; ++nb)
#pragma unroll
            for (int i = 0; i < 4; ++i) oacc[nb][i] *= alr[i];

        // O += P V : A = P [q][j] (b128 from LDS), B = V^T [d][j] (b128 global)
        const bf16x8 p0 = *(const bf16x8*)(&Ps[wave][lm][quad * 8]);
        const bf16x8 p1 = *(const bf16x8*)(&Ps[wave][lm][32 + quad * 8]);
#pragma unroll
        for (int nb = 0; nb < 4; ++nb) {
            const size_t vrow = (size_t)(nb * 16 + lm) * 1024 + kt * 64;
            bf16x8 v0 = *(const bf16x8*)(Vtg + vrow + quad * 8);
            bf16x8 v1 = *(const bf16x8*)(Vtg + vrow + 32 + quad * 8);
            oacc[nb] = __builtin_amdgcn_mfma_f32_16x16x32_bf16(p0, v0, oacc[nb], 0, 0, 0);
            oacc[nb] = __builtin_amdgcn_mfma_f32_16x16x32_bf16(p1, v1, oacc[nb], 0, 0, 0);
        }
    }

    // epilogue: O / li -> y (B,T,C) bf16 (oacc row = q local quad*4+i, col = d)
    const float linv = 1.0f / li;
    float invr[4];
#pragma unroll
    for (int i = 0; i < 4; ++i) invr[i] = __shfl(linv, quad * 4 + i, 64);
#pragma unroll
    for (int nb = 0; nb < 4; ++nb)
#pragma unroll
        for (int i = 0; i < 4; ++i) {
            const int qq = qb + wave * 16 + quad * 4 + i;
            const int d = nb * 16 + lm;
            y[((size_t)(b * 1024 + qq)) * 1024 + h * 64 + d] = f2bf(oacc[nb][i] * invr[i]);
        }
}

extern "C" void kernel_launch(void* const* d_in, const int* in_sizes, int n_in,
                              void* d_out, int out_size, void* d_ws, size_t ws_size,
                              hipStream_t stream) {
    const float* x      = (const float*)d_in[0];
    const float* qkv_w  = (const float*)d_in[1];
    const float* qkv_b  = (const float*)d_in[2];
    const float* proj_w = (const float*)d_in[3];
    const float* proj_b = (const float*)d_in[4];
    const float* rel    = (const float*)d_in[5];
    float* out = (float*)d_out;

    char* ws = (char*)d_ws;
    unsigned short* xb   = (unsigned short*)(ws + 0);
    unsigned short* qwb  = (unsigned short*)(ws + 8388608);
    unsigned short* pwb  = (unsigned short*)(ws + 14680064);
    float* table         = (float*)(ws + 16777216);
    unsigned short* qkvb = (unsigned short*)(ws + 16908288);
    unsigned short* yb   = (unsigned short*)(ws + 42074112);

    cvt3<<<4096, 256, 0, stream>>>(x, qkv_w, proj_w, xb, qwb, pwb);
    table_reduce<<<2047, 256, 0, stream>>>(rel, table);
    gemm_bt<0><<<dim3(32, 24), 512, 0, stream>>>(xb, qwb, qkv_b, qkvb, nullptr,
                                                 4096, 3072, 1024);
    attn_mfma<<<dim3(64, 8), 512, 0, stream>>>(qkvb, table, yb);
    gemm_bt<1><<<dim3(32, 8), 512, 0, stream>>>(yb, pwb, proj_b, nullptr, out,
                                                4096, 1024, 1024);
}

// Round 5
// 222.952 us; speedup vs baseline: 1.0968x; 1.0968x over previous
//
#include <hip/hip_runtime.h>
#include <hip/hip_bf16.h>
#include <cstdint>

// Problem: B=4, T=1024, C=1024, H=16, D=64, MAX_LEN=1024, NPOS=2047
// Pipeline (R15, resubmitted unchanged in R16 -- GPU timeout, never measured):
//   cvt3: x, qkv_w, proj_w fp32 -> bf16 in ws (one pass)
//   table_reduce rel_pos_emb -> (2047,16)
//   gemm_bt<0>: qkv = xb @ qwb^T + b -> scatter bf16; Q,K (B,H,T,D), V (B,H,D,T)
//   attn_mfma: flash causal, 128-query blocks (8 waves), S^T-softmax -> y bf16
//   gemm_bt<1>: out = y @ pwb^T + b -> fp32 d_out
//
// R13 measured (no-LDS attn): 92.9us, MfmaUtil 3.9%, VALU 14.8%, HBM 2.9%,
// occ 26% (grid-capped: 512 blocks/256CU = 50% max), VGPR 36. Latency-bound:
// K/V L2 loads sit on the MFMA dep chain, ~2 waves/SIMD can't hide them.
// R15 changes (attn only):
//  1. Register pipeline: K double-buffered one tile ahead (kA/kB ping-pong,
//     2x unroll; ktiles always even). V issued at iteration TOP, consumed
//     at PV after ~500cy of QK+softmax (T14 issue-early). VGPR ~170 is free
//     (grid caps occupancy, not VGPR).
//  2. PV operand swap: mfma(A=V^T,B=P) -> O^T[row=d][col=q=lm]. C/D rule:
//     row=A-rows, col=B-rows (verified m89). alpha & 1/li are per-lane
//     (q==lm): deletes 4 bcast shfls/tile + 4 epilogue shfls; epilogue
//     packs 4 consecutive d (i=0..3) into one int2 store.
//
// Workspace layout (bytes):
//   xb   @ 0         : 4096x1024 bf16  (8 MB)
//   qwb  @ 8388608   : 3072x1024 bf16  (6 MB)
//   pwb  @ 14680064  : 1024x1024 bf16  (2 MB)
//   table@ 16777216  : 2047x16 f32     (128 KB)
//   qkvb @ 16908288  : (3,4,16,64K) bf16 (24 MB)
//   y    @ 42074112  : 4096x1024 bf16  (8 MB)

typedef __bf16 bf16x8 __attribute__((ext_vector_type(8)));
typedef float f32x4 __attribute__((ext_vector_type(4)));

__device__ __forceinline__ float bf2f(unsigned short u) {
    return __uint_as_float(((unsigned)u) << 16);
}
__device__ __forceinline__ unsigned short f2bf(float f) {
    __hip_bfloat16 h = __float2bfloat16(f);
    return *reinterpret_cast<unsigned short*>(&h);
}
__device__ __forceinline__ int4 cvt8(float4 a, float4 b) {
    union { unsigned short s[8]; int4 v; } u;
    u.s[0] = f2bf(a.x); u.s[1] = f2bf(a.y); u.s[2] = f2bf(a.z); u.s[3] = f2bf(a.w);
    u.s[4] = f2bf(b.x); u.s[5] = f2bf(b.y); u.s[6] = f2bf(b.z); u.s[7] = f2bf(b.w);
    return u.v;
}

// async global->LDS, 16B per lane. LDS dest must be linear base+lane*16.
__device__ __forceinline__ void gload16(const void* g, void* l) {
    __builtin_amdgcn_global_load_lds(
        reinterpret_cast<const __attribute__((address_space(1))) unsigned int*>(
            reinterpret_cast<uintptr_t>(g)),
        reinterpret_cast<__attribute__((address_space(3))) unsigned int*>(
            reinterpret_cast<uintptr_t>(l)),
        16, 0, 0);
}

// ---------------- fp32 -> bf16 one-shot convert (x, qkv_w, proj_w) ----------
__global__ __launch_bounds__(256) void cvt3(const float* __restrict__ x,
                                            const float* __restrict__ w1,
                                            const float* __restrict__ w2,
                                            unsigned short* __restrict__ ox,
                                            unsigned short* __restrict__ ow1,
                                            unsigned short* __restrict__ ow2) {
    const int i = blockIdx.x * 256 + threadIdx.x;
    const float* s; unsigned short* d; int li;
    if (i < 524288)      { s = x;  d = ox;  li = i; }
    else if (i < 917504) { s = w1; d = ow1; li = i - 524288; }
    else                 { s = w2; d = ow2; li = i - 917504; }
    const float4 a = *(const float4*)(s + (size_t)li * 8);
    const float4 b = *(const float4*)(s + (size_t)li * 8 + 4);
    *(int4*)(d + (size_t)li * 8) = cvt8(a, b);
}

// ---------------- rel_pos_emb (2047,1024) -> table (2047,16) ----------------
__global__ __launch_bounds__(256) void table_reduce(const float* __restrict__ rel,
                                                    float* __restrict__ table) {
    const int p = blockIdx.x;
    const int tid = threadIdx.x, lane = tid & 63, wave = tid >> 6;
    const float* r = rel + (size_t)p * 1024;
    float s[4];
#pragma unroll
    for (int k = 0; k < 4; ++k) s[k] = r[tid + 256 * k];
#pragma unroll
    for (int k = 0; k < 4; ++k) {
        float v = s[k];
        for (int o = 32; o; o >>= 1) v += __shfl_xor(v, o, 64);
        if (lane == 0) table[p * 16 + wave + 4 * k] = v;
    }
}

// ---------------- bf16 MFMA GEMM: C = A B^T + bias (gload_lds / m97) --------
// Unchanged from R12 (measured win: MfmaUtil 31.9%, occ 74.8%).
template <int EPI>
__global__ __launch_bounds__(512) void gemm_bt(const unsigned short* __restrict__ A,
                                               const unsigned short* __restrict__ B,
                                               const float* __restrict__ bias,
                                               unsigned short* __restrict__ outb,
                                               float* __restrict__ outf,
                                               int M, int N, int K) {
    __shared__ __attribute__((aligned(16))) unsigned short As[128 * 32];
    __shared__ __attribute__((aligned(16))) unsigned short Bs[128 * 32];
    const int bm = blockIdx.x * 128, bn = blockIdx.y * 128;
    const int tid = threadIdx.x, lane = tid & 63, wave = tid >> 6;
    const int wr = wave & 1, wc = wave >> 1;  // wc in 0..3
    const int quad = lane >> 4, lm = lane & 15;

    const int srow = tid >> 2;        // 0..127
    const int scol = (tid & 3) * 8;   // shorts
    const unsigned short* Ap = A + (size_t)(bm + srow) * K + scol;
    const unsigned short* Bp = B + (size_t)(bn + srow) * K + scol;
    unsigned short* AsW = &As[tid * 8];   // == row srow, col scol (linear)
    unsigned short* BsW = &Bs[tid * 8];

    f32x4 acc[4][2];
#pragma unroll
    for (int r = 0; r < 4; ++r)
#pragma unroll
        for (int c = 0; c < 2; ++c) acc[r][c] = (f32x4){0.f, 0.f, 0.f, 0.f};

    for (int kk = 0; kk < K; kk += 32) {
        gload16(Ap + kk, AsW);
        gload16(Bp + kk, BsW);
        __syncthreads();  // compiler emits vmcnt(0) drain before s_barrier

        bf16x8 af[4], bfr[2];
#pragma unroll
        for (int r = 0; r < 4; ++r)
            af[r] = *(const bf16x8*)(&As[(64 * wr + 16 * r + lm) * 32 + quad * 8]);
#pragma unroll
        for (int c = 0; c < 2; ++c)
            bfr[c] = *(const bf16x8*)(&Bs[(32 * wc + 16 * c + lm) * 32 + quad * 8]);
#pragma unroll
        for (int r = 0; r < 4; ++r)
#pragma unroll
            for (int c = 0; c < 2; ++c)
                acc[r][c] = __builtin_amdgcn_mfma_f32_16x16x32_bf16(af[r], bfr[c], acc[r][c], 0, 0, 0);
        __syncthreads();
    }

    // C/D layout: col = lane&15, row = (lane>>4)*4 + reg
#pragma unroll
    for (int r = 0; r < 4; ++r)
#pragma unroll
        for (int c = 0; c < 2; ++c)
#pragma unroll
            for (int i = 0; i < 4; ++i) {
                const int row = bm + 64 * wr + 16 * r + quad * 4 + i;
                const int col = bn + 32 * wc + 16 * c + lm;
                const float v = acc[r][c][i] + bias[col];
                if (EPI == 0) {
                    const int b = row >> 10, t = row & 1023;
                    const int s3 = col >> 10, rem = col & 1023;
                    const int h = rem >> 6, d = rem & 63;
                    const size_t base = (((size_t)s3 * 4 + b) * 16 + h) * 65536;
                    const size_t off = base + (s3 == 2 ? (size_t)d * 1024 + t
                                                       : (size_t)t * 64 + d);
                    outb[off] = f2bf(v);
                } else {
                    outf[(size_t)row * N + col] = v;
                }
            }
}

// ---------------- MFMA flash causal attention, S^T-softmax ----------------
// grid (B*H, T/128), block 512 = 8 waves, no per-tile barriers (R13).
// R15: K reg-double-buffered one tile ahead; V issued at iter top, consumed
// at PV (hidden under QK+softmax). PV operand-swapped: oacc[nb][i] =
// O^T[d = nb*16+quad*4+i][q = lm] -> alpha/linv per-lane, int2 epilogue.

#define LOADK(DST, KT)                                                        \
    do {                                                                      \
        _Pragma("unroll")                                                     \
        for (int nb = 0; nb < 4; ++nb) {                                      \
            const size_t kr = (size_t)((KT) * 64 + nb * 16 + lm) * 64;        \
            DST[nb * 2]     = *(const bf16x8*)(Kg + kr + quad * 8);           \
            DST[nb * 2 + 1] = *(const bf16x8*)(Kg + kr + 32 + quad * 8);      \
        }                                                                     \
    } while (0)

#define ATTN_TILE(KF, KT)                                                     \
    do {                                                                      \
        const int kt_ = (KT);                                                 \
        /* V for THIS tile: issue first, consume after softmax (~500cy) */    \
        bf16x8 vf[8];                                                         \
        _Pragma("unroll")                                                     \
        for (int nb = 0; nb < 4; ++nb) {                                      \
            const size_t vr = (size_t)(nb * 16 + lm) * 1024 + (size_t)kt_ * 64; \
            vf[nb * 2]     = *(const bf16x8*)(Vtg + vr + quad * 8);           \
            vf[nb * 2 + 1] = *(const bf16x8*)(Vtg + vr + 32 + quad * 8);      \
        }                                                                     \
        /* S^T = K Q^T (A = K rows j, B = Q rows q) */                        \
        f32x4 s[4];                                                           \
        _Pragma("unroll")                                                     \
        for (int nb = 0; nb < 4; ++nb) {                                      \
            s[nb] = (f32x4){0.f, 0.f, 0.f, 0.f};                              \
            s[nb] = __builtin_amdgcn_mfma_f32_16x16x32_bf16(KF[nb * 2], qf0, s[nb], 0, 0, 0); \
            s[nb] = __builtin_amdgcn_mfma_f32_16x16x32_bf16(KF[nb * 2 + 1], qf1, s[nb], 0, 0, 0); \
        }                                                                     \
        /* scale + rel-pos bias + causal mask (q lane-constant) */            \
        const int jb0 = kt_ * 64 + quad * 4;                                  \
        _Pragma("unroll")                                                     \
        for (int nb = 0; nb < 4; ++nb)                                        \
            _Pragma("unroll")                                                 \
            for (int i = 0; i < 4; ++i) {                                     \
                const int j = jb0 + nb * 16 + i;                              \
                const float v = fmaf(s[nb][i], 0.125f, tb[q - j + 127]);      \
                s[nb][i] = (j <= q) ? v : -1e30f;                             \
            }                                                                 \
        /* online softmax: 16-reg tree + cross-quad shfls (xor 16,32) */      \
        float mx = -1e30f;                                                    \
        _Pragma("unroll")                                                     \
        for (int nb = 0; nb < 4; ++nb)                                        \
            _Pragma("unroll")                                                 \
            for (int i = 0; i < 4; ++i) mx = fmaxf(mx, s[nb][i]);             \
        mx = fmaxf(mx, __shfl_xor(mx, 16, 64));                               \
        mx = fmaxf(mx, __shfl_xor(mx, 32, 64));                               \
        const float mnew = fmaxf(mi, mx);                                     \
        const float alpha = __expf(mi - mnew);                                \
        mi = mnew;                                                            \
        _Pragma("unroll")                                                     \
        for (int nb = 0; nb < 4; ++nb)                                        \
            _Pragma("unroll")                                                 \
            for (int i = 0; i < 4; ++i) s[nb][i] = __expf(s[nb][i] - mnew);   \
        float psum = 0.f;                                                     \
        _Pragma("unroll")                                                     \
        for (int nb = 0; nb < 4; ++nb)                                        \
            psum += (s[nb][0] + s[nb][1]) + (s[nb][2] + s[nb][3]);            \
        psum += __shfl_xor(psum, 16, 64);                                     \
        psum += __shfl_xor(psum, 32, 64);                                     \
        li = li * alpha + psum;                                               \
        /* P bounce: [wave][q=lm][j] cross-quad redistribution (wave-priv) */ \
        _Pragma("unroll")                                                     \
        for (int nb = 0; nb < 4; ++nb) {                                      \
            union { unsigned short u[4]; int2 v; } p4;                        \
            p4.u[0] = f2bf(s[nb][0]);                                         \
            p4.u[1] = f2bf(s[nb][1]);                                         \
            p4.u[2] = f2bf(s[nb][2]);                                         \
            p4.u[3] = f2bf(s[nb][3]);                                         \
            *(int2*)(&Ps[wave][lm][nb * 16 + quad * 4]) = p4.v;               \
        }                                                                     \
        /* alpha per-lane (oacc col = q = lm): no broadcast */                \
        _Pragma("unroll")                                                     \
        for (int nb = 0; nb < 4; ++nb)                                        \
            _Pragma("unroll")                                                 \
            for (int i = 0; i < 4; ++i) oacc[nb][i] *= alpha;                 \
        const bf16x8 p0 = *(const bf16x8*)(&Ps[wave][lm][quad * 8]);          \
        const bf16x8 p1 = *(const bf16x8*)(&Ps[wave][lm][32 + quad * 8]);     \
        /* O^T += V^T P^T : A = V^T rows d, B = P rows q */                   \
        _Pragma("unroll")                                                     \
        for (int nb = 0; nb < 4; ++nb) {                                      \
            oacc[nb] = __builtin_amdgcn_mfma_f32_16x16x32_bf16(vf[nb * 2], p0, oacc[nb], 0, 0, 0); \
            oacc[nb] = __builtin_amdgcn_mfma_f32_16x16x32_bf16(vf[nb * 2 + 1], p1, oacc[nb], 0, 0, 0); \
        }                                                                     \
    } while (0)

__global__ __launch_bounds__(512) void attn_mfma(const unsigned short* __restrict__ qkvb,
                                                 const float* __restrict__ table,
                                                 unsigned short* __restrict__ y) {
    const int bh = blockIdx.x, b = bh >> 4, h = bh & 15;
    const int qb = (7 - blockIdx.y) * 128;  // longest blocks first
    const int tid = threadIdx.x, lane = tid & 63, wave = tid >> 6;
    const int quad = lane >> 4, lm = lane & 15;

    __shared__ __attribute__((aligned(16))) unsigned short Ps[8][16][72];   // [wave][q][j]
    __shared__ float tb[1280];

    const unsigned short* Qg  = qkvb + ((size_t)(b)*16 + h) * 65536;       // [t][d]
    const unsigned short* Kg  = qkvb + ((size_t)(4 + b)*16 + h) * 65536;   // [t][d]
    const unsigned short* Vtg = qkvb + ((size_t)(8 + b)*16 + h) * 65536;   // [d][t]

    // Q fragment (MFMA B-operand in QK^T)
    const bf16x8 qf0 = *(const bf16x8*)(Qg + (size_t)(qb + wave * 16 + lm) * 64 + quad * 8);
    const bf16x8 qf1 = *(const bf16x8*)(Qg + (size_t)(qb + wave * 16 + lm) * 64 + 32 + quad * 8);

    const int tbn = qb + 255;
    for (int i = tid; i < tbn; i += 512) tb[i] = table[(896 + i) * 16 + h];
    __syncthreads();  // tb ready; only block-wide sync in the kernel

    f32x4 oacc[4];
#pragma unroll
    for (int nb = 0; nb < 4; ++nb) oacc[nb] = (f32x4){0.f, 0.f, 0.f, 0.f};
    float mi = -1e30f, li = 0.f;  // per-lane: one query q = qb + wave*16 + lm

    const int q = qb + wave * 16 + lm;
    const int ktiles = qb / 64 + 2;  // always even (qb multiple of 128)

    bf16x8 kA[8], kB[8];
    LOADK(kA, 0);
    for (int kt = 0; kt < ktiles; kt += 2) {
        LOADK(kB, kt + 1);            // next tile's K: full iteration of cover
        ATTN_TILE(kA, kt);
        if (kt + 2 < ktiles) LOADK(kA, kt + 2);
        ATTN_TILE(kB, kt + 1);
    }

    // epilogue: O^T/li -> y (B,T,C) bf16. Lane q = lm; d = nb*16+quad*4+i
    // (4 consecutive d per nb -> int2 store).
    const float linv = 1.0f / li;
#pragma unroll
    for (int nb = 0; nb < 4; ++nb) {
        union { unsigned short u[4]; int2 v; } o4;
#pragma unroll
        for (int i = 0; i < 4; ++i) o4.u[i] = f2bf(oacc[nb][i] * linv);
        *(int2*)(y + ((size_t)(b * 1024 + q)) * 1024 + h * 64 + nb * 16 + quad * 4) = o4.v;
    }
}

extern "C" void kernel_launch(void* const* d_in, const int* in_sizes, int n_in,
                              void* d_out, int out_size, void* d_ws, size_t ws_size,
                              hipStream_t stream) {
    const float* x      = (const float*)d_in[0];
    const float* qkv_w  = (const float*)d_in[1];
    const float* qkv_b  = (const float*)d_in[2];
    const float* proj_w = (const float*)d_in[3];
    const float* proj_b = (const float*)d_in[4];
    const float* rel    = (const float*)d_in[5];
    float* out = (float*)d_out;

    char* ws = (char*)d_ws;
    unsigned short* xb   = (unsigned short*)(ws + 0);
    unsigned short* qwb  = (unsigned short*)(ws + 8388608);
    unsigned short* pwb  = (unsigned short*)(ws + 14680064);
    float* table         = (float*)(ws + 16777216);
    unsigned short* qkvb = (unsigned short*)(ws + 16908288);
    unsigned short* yb   = (unsigned short*)(ws + 42074112);

    cvt3<<<4096, 256, 0, stream>>>(x, qkv_w, proj_w, xb, qwb, pwb);
    table_reduce<<<2047, 256, 0, stream>>>(rel, table);
    gemm_bt<0><<<dim3(32, 24), 512, 0, stream>>>(xb, qwb, qkv_b, qkvb, nullptr,
                                                 4096, 3072, 1024);
    attn_mfma<<<dim3(64, 8), 512, 0, stream>>>(qkvb, table, yb);
    gemm_bt<1><<<dim3(32, 8), 512, 0, stream>>>(yb, pwb, proj_b, nullptr, out,
                                                4096, 1024, 1024);
}

// Round 6
// 221.700 us; speedup vs baseline: 1.1030x; 1.0056x over previous
//
#include <hip/hip_runtime.h>
#include <hip/hip_bf16.h>
#include <cstdint>

// Problem: B=4, T=1024, C=1024, H=16, D=64, MAX_LEN=1024, NPOS=2047
// Pipeline (R17):
//   cvt3: x, qkv_w, proj_w fp32 -> bf16 in ws (one pass)
//   table_reduce rel_pos_emb -> (2047,16)
//   gemm_bt<0>: qkv = xb @ qwb^T + b -> scatter bf16; Q,K (B,H,T,D), V (B,H,D,T)
//   attn_mfma: flash causal, level-gridded 4-wave blocks -> y bf16
//   gemm_bt<1>: out = y @ pwb^T + b -> fp32 d_out
//
// R15 measured: attn 72.0us, MfmaUtil 4.9%, VALU 17.6%, occ 20.6%, VGPR 80.
// Reg-pipeline+operand-swap confirmed (-21us) but still latency-bound; the
// binding constraint is occupancy: 512x8-wave blocks = 2 blocks/CU with 8:1
// causal duration spread -> time-avg 1.65 waves/SIMD.
// R17 change (re-grid ONLY, wave body identical): 256-thr blocks, grid
// (64 bh, 16 levels). Level k = slices {4k..4k+3}; all 4 waves have ktiles
// = k+1 exactly (intra-block uniform, exact causal work). 1024 blocks,
// longest-first; VGPR 80 < 128 -> 4 blocks/CU = 16 waves/CU cap. Odd ktiles
// via tail tile (no masked dummy).
//
// Workspace layout (bytes):
//   xb   @ 0         : 4096x1024 bf16  (8 MB)
//   qwb  @ 8388608   : 3072x1024 bf16  (6 MB)
//   pwb  @ 14680064  : 1024x1024 bf16  (2 MB)
//   table@ 16777216  : 2047x16 f32     (128 KB)
//   qkvb @ 16908288  : (3,4,16,64K) bf16 (24 MB)
//   y    @ 42074112  : 4096x1024 bf16  (8 MB)

typedef __bf16 bf16x8 __attribute__((ext_vector_type(8)));
typedef float f32x4 __attribute__((ext_vector_type(4)));

__device__ __forceinline__ float bf2f(unsigned short u) {
    return __uint_as_float(((unsigned)u) << 16);
}
__device__ __forceinline__ unsigned short f2bf(float f) {
    __hip_bfloat16 h = __float2bfloat16(f);
    return *reinterpret_cast<unsigned short*>(&h);
}
__device__ __forceinline__ int4 cvt8(float4 a, float4 b) {
    union { unsigned short s[8]; int4 v; } u;
    u.s[0] = f2bf(a.x); u.s[1] = f2bf(a.y); u.s[2] = f2bf(a.z); u.s[3] = f2bf(a.w);
    u.s[4] = f2bf(b.x); u.s[5] = f2bf(b.y); u.s[6] = f2bf(b.z); u.s[7] = f2bf(b.w);
    return u.v;
}

// async global->LDS, 16B per lane. LDS dest must be linear base+lane*16.
__device__ __forceinline__ void gload16(const void* g, void* l) {
    __builtin_amdgcn_global_load_lds(
        reinterpret_cast<const __attribute__((address_space(1))) unsigned int*>(
            reinterpret_cast<uintptr_t>(g)),
        reinterpret_cast<__attribute__((address_space(3))) unsigned int*>(
            reinterpret_cast<uintptr_t>(l)),
        16, 0, 0);
}

// ---------------- fp32 -> bf16 one-shot convert (x, qkv_w, proj_w) ----------
__global__ __launch_bounds__(256) void cvt3(const float* __restrict__ x,
                                            const float* __restrict__ w1,
                                            const float* __restrict__ w2,
                                            unsigned short* __restrict__ ox,
                                            unsigned short* __restrict__ ow1,
                                            unsigned short* __restrict__ ow2) {
    const int i = blockIdx.x * 256 + threadIdx.x;
    const float* s; unsigned short* d; int li;
    if (i < 524288)      { s = x;  d = ox;  li = i; }
    else if (i < 917504) { s = w1; d = ow1; li = i - 524288; }
    else                 { s = w2; d = ow2; li = i - 917504; }
    const float4 a = *(const float4*)(s + (size_t)li * 8);
    const float4 b = *(const float4*)(s + (size_t)li * 8 + 4);
    *(int4*)(d + (size_t)li * 8) = cvt8(a, b);
}

// ---------------- rel_pos_emb (2047,1024) -> table (2047,16) ----------------
__global__ __launch_bounds__(256) void table_reduce(const float* __restrict__ rel,
                                                    float* __restrict__ table) {
    const int p = blockIdx.x;
    const int tid = threadIdx.x, lane = tid & 63, wave = tid >> 6;
    const float* r = rel + (size_t)p * 1024;
    float s[4];
#pragma unroll
    for (int k = 0; k < 4; ++k) s[k] = r[tid + 256 * k];
#pragma unroll
    for (int k = 0; k < 4; ++k) {
        float v = s[k];
        for (int o = 32; o; o >>= 1) v += __shfl_xor(v, o, 64);
        if (lane == 0) table[p * 16 + wave + 4 * k] = v;
    }
}

// ---------------- bf16 MFMA GEMM: C = A B^T + bias (gload_lds / m97) --------
// Unchanged from R12 (measured win: MfmaUtil 31.9%, occ 74.8%).
template <int EPI>
__global__ __launch_bounds__(512) void gemm_bt(const unsigned short* __restrict__ A,
                                               const unsigned short* __restrict__ B,
                                               const float* __restrict__ bias,
                                               unsigned short* __restrict__ outb,
                                               float* __restrict__ outf,
                                               int M, int N, int K) {
    __shared__ __attribute__((aligned(16))) unsigned short As[128 * 32];
    __shared__ __attribute__((aligned(16))) unsigned short Bs[128 * 32];
    const int bm = blockIdx.x * 128, bn = blockIdx.y * 128;
    const int tid = threadIdx.x, lane = tid & 63, wave = tid >> 6;
    const int wr = wave & 1, wc = wave >> 1;  // wc in 0..3
    const int quad = lane >> 4, lm = lane & 15;

    const int srow = tid >> 2;        // 0..127
    const int scol = (tid & 3) * 8;   // shorts
    const unsigned short* Ap = A + (size_t)(bm + srow) * K + scol;
    const unsigned short* Bp = B + (size_t)(bn + srow) * K + scol;
    unsigned short* AsW = &As[tid * 8];   // == row srow, col scol (linear)
    unsigned short* BsW = &Bs[tid * 8];

    f32x4 acc[4][2];
#pragma unroll
    for (int r = 0; r < 4; ++r)
#pragma unroll
        for (int c = 0; c < 2; ++c) acc[r][c] = (f32x4){0.f, 0.f, 0.f, 0.f};

    for (int kk = 0; kk < K; kk += 32) {
        gload16(Ap + kk, AsW);
        gload16(Bp + kk, BsW);
        __syncthreads();  // compiler emits vmcnt(0) drain before s_barrier

        bf16x8 af[4], bfr[2];
#pragma unroll
        for (int r = 0; r < 4; ++r)
            af[r] = *(const bf16x8*)(&As[(64 * wr + 16 * r + lm) * 32 + quad * 8]);
#pragma unroll
        for (int c = 0; c < 2; ++c)
            bfr[c] = *(const bf16x8*)(&Bs[(32 * wc + 16 * c + lm) * 32 + quad * 8]);
#pragma unroll
        for (int r = 0; r < 4; ++r)
#pragma unroll
            for (int c = 0; c < 2; ++c)
                acc[r][c] = __builtin_amdgcn_mfma_f32_16x16x32_bf16(af[r], bfr[c], acc[r][c], 0, 0, 0);
        __syncthreads();
    }

    // C/D layout: col = lane&15, row = (lane>>4)*4 + reg
#pragma unroll
    for (int r = 0; r < 4; ++r)
#pragma unroll
        for (int c = 0; c < 2; ++c)
#pragma unroll
            for (int i = 0; i < 4; ++i) {
                const int row = bm + 64 * wr + 16 * r + quad * 4 + i;
                const int col = bn + 32 * wc + 16 * c + lm;
                const float v = acc[r][c][i] + bias[col];
                if (EPI == 0) {
                    const int b = row >> 10, t = row & 1023;
                    const int s3 = col >> 10, rem = col & 1023;
                    const int h = rem >> 6, d = rem & 63;
                    const size_t base = (((size_t)s3 * 4 + b) * 16 + h) * 65536;
                    const size_t off = base + (s3 == 2 ? (size_t)d * 1024 + t
                                                       : (size_t)t * 64 + d);
                    outb[off] = f2bf(v);
                } else {
                    outf[(size_t)row * N + col] = v;
                }
            }
}

// ---------------- MFMA flash causal attention, S^T-softmax ----------------
// R17 grid (64 bh, 16 levels), block 256 = 4 waves, no per-tile barriers.
// Level k = 15 - blockIdx.y (longest first). Wave w owns slice s = 4k+w:
// queries q = 16s + lm, exact ktiles = k+1 (same for all 4 waves -> uniform
// block duration). Wave body identical to R15: K reg-dbuf one tile ahead,
// V issued at iter top, PV operand-swapped (O^T, per-lane alpha/linv).

#define LOADK(DST, KT)                                                        \
    do {                                                                      \
        _Pragma("unroll")                                                     \
        for (int nb = 0; nb < 4; ++nb) {                                      \
            const size_t kr = (size_t)((KT) * 64 + nb * 16 + lm) * 64;        \
            DST[nb * 2]     = *(const bf16x8*)(Kg + kr + quad * 8);           \
            DST[nb * 2 + 1] = *(const bf16x8*)(Kg + kr + 32 + quad * 8);      \
        }                                                                     \
    } while (0)

#define ATTN_TILE(KF, KT)                                                     \
    do {                                                                      \
        const int kt_ = (KT);                                                 \
        /* V for THIS tile: issue first, consume after softmax (~500cy) */    \
        bf16x8 vf[8];                                                         \
        _Pragma("unroll")                                                     \
        for (int nb = 0; nb < 4; ++nb) {                                      \
            const size_t vr = (size_t)(nb * 16 + lm) * 1024 + (size_t)kt_ * 64; \
            vf[nb * 2]     = *(const bf16x8*)(Vtg + vr + quad * 8);           \
            vf[nb * 2 + 1] = *(const bf16x8*)(Vtg + vr + 32 + quad * 8);      \
        }                                                                     \
        /* S^T = K Q^T (A = K rows j, B = Q rows q) */                        \
        f32x4 s[4];                                                           \
        _Pragma("unroll")                                                     \
        for (int nb = 0; nb < 4; ++nb) {                                      \
            s[nb] = (f32x4){0.f, 0.f, 0.f, 0.f};                              \
            s[nb] = __builtin_amdgcn_mfma_f32_16x16x32_bf16(KF[nb * 2], qf0, s[nb], 0, 0, 0); \
            s[nb] = __builtin_amdgcn_mfma_f32_16x16x32_bf16(KF[nb * 2 + 1], qf1, s[nb], 0, 0, 0); \
        }                                                                     \
        /* scale + rel-pos bias + causal mask (q lane-constant) */            \
        const int jb0 = kt_ * 64 + quad * 4;                                  \
        _Pragma("unroll")                                                     \
        for (int nb = 0; nb < 4; ++nb)                                        \
            _Pragma("unroll")                                                 \
            for (int i = 0; i < 4; ++i) {                                     \
                const int j = jb0 + nb * 16 + i;                              \
                const float v = fmaf(s[nb][i], 0.125f, tb[q - j + 127]);      \
                s[nb][i] = (j <= q) ? v : -1e30f;                             \
            }                                                                 \
        /* online softmax: 16-reg tree + cross-quad shfls (xor 16,32) */      \
        float mx = -1e30f;                                                    \
        _Pragma("unroll")                                                     \
        for (int nb = 0; nb < 4; ++nb)                                        \
            _Pragma("unroll")                                                 \
            for (int i = 0; i < 4; ++i) mx = fmaxf(mx, s[nb][i]);             \
        mx = fmaxf(mx, __shfl_xor(mx, 16, 64));                               \
        mx = fmaxf(mx, __shfl_xor(mx, 32, 64));                               \
        const float mnew = fmaxf(mi, mx);                                     \
        const float alpha = __expf(mi - mnew);                                \
        mi = mnew;                                                            \
        _Pragma("unroll")                                                     \
        for (int nb = 0; nb < 4; ++nb)                                        \
            _Pragma("unroll")                                                 \
            for (int i = 0; i < 4; ++i) s[nb][i] = __expf(s[nb][i] - mnew);   \
        float psum = 0.f;                                                     \
        _Pragma("unroll")                                                     \
        for (int nb = 0; nb < 4; ++nb)                                        \
            psum += (s[nb][0] + s[nb][1]) + (s[nb][2] + s[nb][3]);            \
        psum += __shfl_xor(psum, 16, 64);                                     \
        psum += __shfl_xor(psum, 32, 64);                                     \
        li = li * alpha + psum;                                               \
        /* P bounce: [wave][q=lm][j] cross-quad redistribution (wave-priv) */ \
        _Pragma("unroll")                                                     \
        for (int nb = 0; nb < 4; ++nb) {                                      \
            union { unsigned short u[4]; int2 v; } p4;                        \
            p4.u[0] = f2bf(s[nb][0]);                                         \
            p4.u[1] = f2bf(s[nb][1]);                                         \
            p4.u[2] = f2bf(s[nb][2]);                                         \
            p4.u[3] = f2bf(s[nb][3]);                                         \
            *(int2*)(&Ps[wave][lm][nb * 16 + quad * 4]) = p4.v;               \
        }                                                                     \
        /* alpha per-lane (oacc col = q = lm): no broadcast */                \
        _Pragma("unroll")                                                     \
        for (int nb = 0; nb < 4; ++nb)                                        \
            _Pragma("unroll")                                                 \
            for (int i = 0; i < 4; ++i) oacc[nb][i] *= alpha;                 \
        const bf16x8 p0 = *(const bf16x8*)(&Ps[wave][lm][quad * 8]);          \
        const bf16x8 p1 = *(const bf16x8*)(&Ps[wave][lm][32 + quad * 8]);     \
        /* O^T += V^T P^T : A = V^T rows d, B = P rows q */                   \
        _Pragma("unroll")                                                     \
        for (int nb = 0; nb < 4; ++nb) {                                      \
            oacc[nb] = __builtin_amdgcn_mfma_f32_16x16x32_bf16(vf[nb * 2], p0, oacc[nb], 0, 0, 0); \
            oacc[nb] = __builtin_amdgcn_mfma_f32_16x16x32_bf16(vf[nb * 2 + 1], p1, oacc[nb], 0, 0, 0); \
        }                                                                     \
    } while (0)

__global__ __launch_bounds__(256) void attn_mfma(const unsigned short* __restrict__ qkvb,
                                                 const float* __restrict__ table,
                                                 unsigned short* __restrict__ y) {
    const int bh = blockIdx.x, b = bh >> 4, h = bh & 15;
    const int level = 15 - blockIdx.y;      // 15..0, longest blocks first
    const int tid = threadIdx.x, lane = tid & 63, wave = tid >> 6;  // wave 0..3
    const int quad = lane >> 4, lm = lane & 15;

    __shared__ __attribute__((aligned(16))) unsigned short Ps[4][16][72];   // [wave][q][j]
    __shared__ float tb[1152];

    const unsigned short* Qg  = qkvb + ((size_t)(b)*16 + h) * 65536;       // [t][d]
    const unsigned short* Kg  = qkvb + ((size_t)(4 + b)*16 + h) * 65536;   // [t][d]
    const unsigned short* Vtg = qkvb + ((size_t)(8 + b)*16 + h) * 65536;   // [d][t]

    // wave's slice: s = 4*level + wave; 16 queries q = 16s + lm
    const int sl = 4 * level + wave;
    const int q = 16 * sl + lm;
    const int ktiles = level + 1;           // exact causal tile count

    // Q fragment (MFMA B-operand in QK^T)
    const bf16x8 qf0 = *(const bf16x8*)(Qg + (size_t)q * 64 + quad * 8);
    const bf16x8 qf1 = *(const bf16x8*)(Qg + (size_t)q * 64 + 32 + quad * 8);

    // tb[i] = table[(896+i)*16+h]; needed i = q-j+127 in [64, 64*level+190]
    const int tbn = 64 * level + 191;
    for (int i = tid; i < tbn; i += 256) tb[i] = table[(896 + i) * 16 + h];
    __syncthreads();  // tb ready; only block-wide sync in the kernel

    f32x4 oacc[4];
#pragma unroll
    for (int nb = 0; nb < 4; ++nb) oacc[nb] = (f32x4){0.f, 0.f, 0.f, 0.f};
    float mi = -1e30f, li = 0.f;  // per-lane: one query q

    bf16x8 kA[8], kB[8];
    LOADK(kA, 0);
    int kt = 0;
    for (; kt + 2 <= ktiles; kt += 2) {
        LOADK(kB, kt + 1);            // next tile's K: full iteration of cover
        ATTN_TILE(kA, kt);
        if (kt + 2 < ktiles) LOADK(kA, kt + 2);
        ATTN_TILE(kB, kt + 1);
    }
    if (kt < ktiles) ATTN_TILE(kA, kt);   // odd-ktiles tail (kA preloaded)

    // epilogue: O^T/li -> y (B,T,C) bf16. Lane q; d = nb*16+quad*4+i
    // (4 consecutive d per nb -> int2 store).
    const float linv = 1.0f / li;
#pragma unroll
    for (int nb = 0; nb < 4; ++nb) {
        union { unsigned short u[4]; int2 v; } o4;
#pragma unroll
        for (int i = 0; i < 4; ++i) o4.u[i] = f2bf(oacc[nb][i] * linv);
        *(int2*)(y + ((size_t)(b * 1024 + q)) * 1024 + h * 64 + nb * 16 + quad * 4) = o4.v;
    }
}

extern "C" void kernel_launch(void* const* d_in, const int* in_sizes, int n_in,
                              void* d_out, int out_size, void* d_ws, size_t ws_size,
                              hipStream_t stream) {
    const float* x      = (const float*)d_in[0];
    const float* qkv_w  = (const float*)d_in[1];
    const float* qkv_b  = (const float*)d_in[2];
    const float* proj_w = (const float*)d_in[3];
    const float* proj_b = (const float*)d_in[4];
    const float* rel    = (const float*)d_in[5];
    float* out = (float*)d_out;

    char* ws = (char*)d_ws;
    unsigned short* xb   = (unsigned short*)(ws + 0);
    unsigned short* qwb  = (unsigned short*)(ws + 8388608);
    unsigned short* pwb  = (unsigned short*)(ws + 14680064);
    float* table         = (float*)(ws + 16777216);
    unsigned short* qkvb = (unsigned short*)(ws + 16908288);
    unsigned short* yb   = (unsigned short*)(ws + 42074112);

    cvt3<<<4096, 256, 0, stream>>>(x, qkv_w, proj_w, xb, qwb, pwb);
    table_reduce<<<2047, 256, 0, stream>>>(rel, table);
    gemm_bt<0><<<dim3(32, 24), 512, 0, stream>>>(xb, qwb, qkv_b, qkvb, nullptr,
                                                 4096, 3072, 1024);
    attn_mfma<<<dim3(64, 16), 256, 0, stream>>>(qkvb, table, yb);
    gemm_bt<1><<<dim3(32, 8), 512, 0, stream>>>(yb, pwb, proj_b, nullptr, out,
                                                4096, 1024, 1024);
}